// Round 1
// baseline (980.046 us; speedup 1.0000x reference)
//
#include <hip/hip_runtime.h>
#include <hip/hip_bf16.h>

// S4D forward. Sizes fixed per reference.
#define HH 1024
#define LL 2048
#define BB 8
#define NN2 32     // complex modes
#define CT 128     // chunk size
#define NCH 16     // LL / CT

// ---------------------------------------------------------------------------
// Kernel 1: per-(b,h) SSM causal conv via chunked scan + D skip + exact GELU.
// Writes gelu(y) as bf16 into workspace (B,H,L).
// ---------------------------------------------------------------------------
__global__ __launch_bounds__(256) void ssm_kernel(
    const float* __restrict__ u, const float* __restrict__ log_dt,
    const float* __restrict__ log_w_real, const float* __restrict__ w_imag,
    const float* __restrict__ C_re, const float* __restrict__ C_im,
    const float* __restrict__ Dp, __hip_bfloat16* __restrict__ g_out)
{
    __shared__ float  u_s[LL];                 // 8 KB
    __shared__ float2 apow[NN2][CT + 1];       // a^j, j=0..128  (33 KB)
    __shared__ float  k_s[CT];                 // conv kernel taps 0..127
    __shared__ float2 p_s[NCH][NN2];           // per-chunk partial states
    __shared__ float2 cs_s[NCH][NN2];          // C * state-before-chunk
    __shared__ float2 Cn_s[NN2];
    __shared__ float2 dtA_s[NN2];

    const int tid = threadIdx.x;
    const int bh = blockIdx.x;
    const int h  = bh % HH;
    const size_t base = (size_t)bh * LL;

    // per-mode constants (dtA, effective C) -- 32 threads
    if (tid < NN2) {
        const int n = tid;
        float dt  = expf(log_dt[h]);
        float wr  = -expf(log_w_real[n]);      // shape (1,N2)
        float wi  = w_imag[n];
        float dar = wr * dt, dai = wi * dt;
        dtA_s[n] = make_float2(dar, dai);
        // (exp(dtA)-1)/w
        float er = expf(dar);
        float sn, cs;  sincosf(dai, &sn, &cs);
        float exr = er * cs - 1.0f;
        float exi = er * sn;
        float den = wr * wr + wi * wi;
        float fr = (exr * wr + exi * wi) / den;
        float fi = (exi * wr - exr * wi) / den;
        float cre = C_re[h * NN2 + n], cim = C_im[h * NN2 + n];
        Cn_s[n] = make_float2(cre * fr - cim * fi, cre * fi + cim * fr);
    }
    // stage u row
    for (int i = tid; i < LL; i += 256) u_s[i] = u[base + i];
    __syncthreads();

    // a^j table: exp(dtA * j), j = 0..CT
    for (int idx = tid; idx < NN2 * (CT + 1); idx += 256) {
        int n = idx / (CT + 1), j = idx % (CT + 1);
        float2 dA = dtA_s[n];
        float mag = expf(dA.x * (float)j);
        float sn, cs;  sincosf(dA.y * (float)j, &sn, &cs);
        apow[n][j] = make_float2(mag * cs, mag * sn);
    }
    __syncthreads();

    // k[t] = 2 Re sum_n C_n a_n^t, t = 0..CT-1
    if (tid < CT) {
        float sum = 0.f;
        #pragma unroll
        for (int n = 0; n < NN2; ++n) {
            float2 C = Cn_s[n]; float2 ap = apow[n][tid];
            sum += C.x * ap.x - C.y * ap.y;
        }
        k_s[tid] = 2.0f * sum;
    }
    __syncthreads();

    // per-chunk partials: p[c][n] = sum_j a^(CT-1-j) * u[c*CT+j]
    for (int task = tid; task < NCH * NN2; task += 256) {
        int c = task >> 5, n = task & 31;
        float pr = 0.f, pi = 0.f;
        const float* uc = &u_s[c * CT];
        for (int j = 0; j < CT; ++j) {
            float uu = uc[j];
            float2 ap = apow[n][CT - 1 - j];
            pr += ap.x * uu;  pi += ap.y * uu;
        }
        p_s[c][n] = make_float2(pr, pi);
    }
    __syncthreads();

    // inter-chunk scan (16 steps, one thread per mode); stash C*s_before_chunk
    if (tid < NN2) {
        const int n = tid;
        float2 aT = apow[n][CT];
        float2 C  = Cn_s[n];
        float sr = 0.f, si = 0.f;
        for (int c = 0; c < NCH; ++c) {
            cs_s[c][n] = make_float2(C.x * sr - C.y * si, C.x * si + C.y * sr);
            float2 p = p_s[c][n];
            float nsr = aT.x * sr - aT.y * si + p.x;
            float nsi = aT.x * si + aT.y * sr + p.y;
            sr = nsr;  si = nsi;
        }
    }
    __syncthreads();

    const float Dv = Dp[h];
    for (int t = tid; t < LL; t += 256) {
        int c = t >> 7, tt = t & (CT - 1);
        const float* uc = &u_s[c * CT];
        // intra-chunk causal conv
        float acc = 0.f;
        for (int j = 0; j <= tt; ++j) acc += k_s[tt - j] * uc[j];
        // carried-state term: 2 Re( a^(tt+1) * (C*s) )
        float st = 0.f;
        #pragma unroll
        for (int n = 0; n < NN2; ++n) {
            float2 ap = apow[n][tt + 1];
            float2 cs = cs_s[c][n];
            st += ap.x * cs.x - ap.y * cs.y;
        }
        acc += 2.0f * st + Dv * u_s[t];
        // exact GELU
        float gel = 0.5f * acc * (1.0f + erff(acc * 0.70710678118f));
        g_out[base + t] = __float2bfloat16(gel);
    }
}

// ---------------------------------------------------------------------------
// Kernel 2: out[b,o,l] = sum_i W[o,i] * g[b,i,l] + bias[o]
// fp32 LDS-tiled GEMM, 64x64 tile, 4x4 per thread. M=N=1024/2048 exact.
// ---------------------------------------------------------------------------
__global__ __launch_bounds__(256) void out_gemm(
    const float* __restrict__ W, const __hip_bfloat16* __restrict__ g,
    const float* __restrict__ bias, float* __restrict__ out)
{
    __shared__ float Wt[64][17];
    __shared__ float Gt[16][65];

    const int tid = threadIdx.x;
    const int b  = blockIdx.z;
    const int o0 = blockIdx.x * 64;
    const int l0 = blockIdx.y * 64;
    const int tx = tid & 15, ty = tid >> 4;
    const size_t gstride = (size_t)HH * LL;

    float acc[4][4] = {};

    for (int k0 = 0; k0 < HH; k0 += 16) {
        #pragma unroll
        for (int q = 0; q < 4; ++q) {
            int idx = tid + q * 256;
            int r = idx >> 4, cc = idx & 15;
            Wt[r][cc] = W[(size_t)(o0 + r) * HH + k0 + cc];
        }
        #pragma unroll
        for (int q = 0; q < 4; ++q) {
            int idx = tid + q * 256;
            int r = idx >> 6, cc = idx & 63;
            Gt[r][cc] = __bfloat162float(g[(size_t)b * gstride + (size_t)(k0 + r) * LL + l0 + cc]);
        }
        __syncthreads();
        #pragma unroll
        for (int kk = 0; kk < 16; ++kk) {
            float av[4], bv[4];
            #pragma unroll
            for (int m = 0; m < 4; ++m) av[m] = Wt[ty * 4 + m][kk];
            #pragma unroll
            for (int n = 0; n < 4; ++n) bv[n] = Gt[kk][tx * 4 + n];
            #pragma unroll
            for (int m = 0; m < 4; ++m)
                #pragma unroll
                for (int n = 0; n < 4; ++n)
                    acc[m][n] += av[m] * bv[n];
        }
        __syncthreads();
    }

    #pragma unroll
    for (int m = 0; m < 4; ++m) {
        int o = o0 + ty * 4 + m;
        float bo = bias[o];
        #pragma unroll
        for (int n = 0; n < 4; ++n)
            out[((size_t)b * HH + o) * LL + l0 + tx * 4 + n] = acc[m][n] + bo;
    }
}

extern "C" void kernel_launch(void* const* d_in, const int* in_sizes, int n_in,
                              void* d_out, int out_size, void* d_ws, size_t ws_size,
                              hipStream_t stream) {
    const float* u          = (const float*)d_in[0];
    const float* log_dt     = (const float*)d_in[1];
    const float* log_w_real = (const float*)d_in[2];
    const float* w_imag     = (const float*)d_in[3];
    const float* C_re       = (const float*)d_in[4];
    const float* C_im       = (const float*)d_in[5];
    const float* Dp         = (const float*)d_in[6];
    const float* W          = (const float*)d_in[7];
    const float* bias       = (const float*)d_in[8];
    float* out = (float*)d_out;
    __hip_bfloat16* g = (__hip_bfloat16*)d_ws;   // B*H*L bf16 = 33.5 MB

    ssm_kernel<<<dim3(BB * HH), 256, 0, stream>>>(u, log_dt, log_w_real, w_imag,
                                                  C_re, C_im, Dp, g);
    out_gemm<<<dim3(HH / 64, LL / 64, BB), 256, 0, stream>>>(W, g, bias, out);
}

// Round 2
// 423.600 us; speedup vs baseline: 2.3136x; 2.3136x over previous
//
#include <hip/hip_runtime.h>
#include <hip/hip_bf16.h>

#define HH 1024
#define LL 2048
#define BB 8
#define NN2 32     // complex modes
#define CT 128     // chunk size
#define NCH 16     // LL / CT

typedef short bf16x8 __attribute__((ext_vector_type(8)));
typedef float f32x4  __attribute__((ext_vector_type(4)));

static __device__ __forceinline__ unsigned short bfbits(float x) {
    __hip_bfloat16 h = __float2bfloat16(x);
    return *(unsigned short*)&h;
}

// ---------------------------------------------------------------------------
// Kernel 1: per-(b,h) SSM causal conv via chunked scan + D skip + exact GELU.
// Writes gelu(y) as bf16 into g_out (B,H,L)  [stashed in d_out's slack].
// ---------------------------------------------------------------------------
__global__ __launch_bounds__(256) void ssm_kernel(
    const float* __restrict__ u, const float* __restrict__ log_dt,
    const float* __restrict__ log_w_real, const float* __restrict__ w_imag,
    const float* __restrict__ C_re, const float* __restrict__ C_im,
    const float* __restrict__ Dp, __hip_bfloat16* __restrict__ g_out)
{
    __shared__ float  u_s[LL];
    __shared__ float2 apow[NN2][CT + 1];
    __shared__ float  k_s[CT];
    __shared__ float2 p_s[NCH][NN2];
    __shared__ float2 cs_s[NCH][NN2];
    __shared__ float2 Cn_s[NN2];
    __shared__ float2 dtA_s[NN2];

    const int tid = threadIdx.x;
    const int bh = blockIdx.x;
    const int h  = bh % HH;
    const size_t base = (size_t)bh * LL;

    if (tid < NN2) {
        const int n = tid;
        float dt  = expf(log_dt[h]);
        float wr  = -expf(log_w_real[n]);
        float wi  = w_imag[n];
        float dar = wr * dt, dai = wi * dt;
        dtA_s[n] = make_float2(dar, dai);
        float er = expf(dar);
        float sn, cs;  sincosf(dai, &sn, &cs);
        float exr = er * cs - 1.0f;
        float exi = er * sn;
        float den = wr * wr + wi * wi;
        float fr = (exr * wr + exi * wi) / den;
        float fi = (exi * wr - exr * wi) / den;
        float cre = C_re[h * NN2 + n], cim = C_im[h * NN2 + n];
        Cn_s[n] = make_float2(cre * fr - cim * fi, cre * fi + cim * fr);
    }
    for (int i = tid; i < LL; i += 256) u_s[i] = u[base + i];
    __syncthreads();

    for (int idx = tid; idx < NN2 * (CT + 1); idx += 256) {
        int n = idx / (CT + 1), j = idx % (CT + 1);
        float2 dA = dtA_s[n];
        float mag = expf(dA.x * (float)j);
        float sn, cs;  sincosf(dA.y * (float)j, &sn, &cs);
        apow[n][j] = make_float2(mag * cs, mag * sn);
    }
    __syncthreads();

    if (tid < CT) {
        float sum = 0.f;
        #pragma unroll
        for (int n = 0; n < NN2; ++n) {
            float2 C = Cn_s[n]; float2 ap = apow[n][tid];
            sum += C.x * ap.x - C.y * ap.y;
        }
        k_s[tid] = 2.0f * sum;
    }
    __syncthreads();

    for (int task = tid; task < NCH * NN2; task += 256) {
        int c = task >> 5, n = task & 31;
        float pr = 0.f, pi = 0.f;
        const float* uc = &u_s[c * CT];
        for (int j = 0; j < CT; ++j) {
            float uu = uc[j];
            float2 ap = apow[n][CT - 1 - j];
            pr += ap.x * uu;  pi += ap.y * uu;
        }
        p_s[c][n] = make_float2(pr, pi);
    }
    __syncthreads();

    if (tid < NN2) {
        const int n = tid;
        float2 aT = apow[n][CT];
        float2 C  = Cn_s[n];
        float sr = 0.f, si = 0.f;
        for (int c = 0; c < NCH; ++c) {
            cs_s[c][n] = make_float2(C.x * sr - C.y * si, C.x * si + C.y * sr);
            float2 p = p_s[c][n];
            float nsr = aT.x * sr - aT.y * si + p.x;
            float nsi = aT.x * si + aT.y * sr + p.y;
            sr = nsr;  si = nsi;
        }
    }
    __syncthreads();

    const float Dv = Dp[h];
    for (int t = tid; t < LL; t += 256) {
        int c = t >> 7, tt = t & (CT - 1);
        const float* uc = &u_s[c * CT];
        float acc = 0.f;
        for (int j = 0; j <= tt; ++j) acc += k_s[tt - j] * uc[j];
        float st = 0.f;
        #pragma unroll
        for (int n = 0; n < NN2; ++n) {
            float2 ap = apow[n][tt + 1];
            float2 cs = cs_s[c][n];
            st += ap.x * cs.x - ap.y * cs.y;
        }
        acc += 2.0f * st + Dv * u_s[t];
        float gel = 0.5f * acc * (1.0f + erff(acc * 0.70710678118f));
        g_out[base + t] = __float2bfloat16(gel);
    }
}

// ---------------------------------------------------------------------------
// Kernel 2: W (1024x1024 fp32) -> bf16
// ---------------------------------------------------------------------------
__global__ __launch_bounds__(256) void conv_w(
    const float* __restrict__ W, __hip_bfloat16* __restrict__ Wb)
{
    int i = blockIdx.x * 256 + threadIdx.x;     // handles 4 floats
    float4 v = ((const float4*)W)[i];
    ushort4 o;
    o.x = bfbits(v.x); o.y = bfbits(v.y); o.z = bfbits(v.z); o.w = bfbits(v.w);
    ((ushort4*)Wb)[i] = o;
}

// ---------------------------------------------------------------------------
// Kernel 3: transpose g (B,H,L) bf16 -> gT (B,L,H) bf16, 64x64 LDS tiles
// ---------------------------------------------------------------------------
__global__ __launch_bounds__(256) void transpose_g(
    const __hip_bfloat16* __restrict__ g, __hip_bfloat16* __restrict__ gT)
{
    __shared__ __hip_bfloat16 t[64][66];
    const int tid = threadIdx.x;
    const int b  = blockIdx.z;
    const int h0 = blockIdx.x * 64;
    const int l0 = blockIdx.y * 64;

    #pragma unroll
    for (int q = 0; q < 2; ++q) {
        int idx = tid + q * 256;
        int r = idx >> 3, c8 = (idx & 7) * 8;   // r = h offset, c8 = l offset
        uint4 v = *(const uint4*)(g + ((size_t)(b * HH + h0 + r)) * LL + l0 + c8);
        unsigned int* dst = (unsigned int*)&t[r][c8];
        dst[0] = v.x; dst[1] = v.y; dst[2] = v.z; dst[3] = v.w;
    }
    __syncthreads();
    #pragma unroll
    for (int q = 0; q < 2; ++q) {
        int idx = tid + q * 256;
        int r = idx >> 3, c8 = (idx & 7) * 8;   // r = l offset, c8 = h offset
        unsigned short tmp[8];
        #pragma unroll
        for (int j = 0; j < 8; ++j) tmp[j] = *(unsigned short*)&t[c8 + j][r];
        uint4 o;
        o.x = (unsigned)tmp[0] | ((unsigned)tmp[1] << 16);
        o.y = (unsigned)tmp[2] | ((unsigned)tmp[3] << 16);
        o.z = (unsigned)tmp[4] | ((unsigned)tmp[5] << 16);
        o.w = (unsigned)tmp[6] | ((unsigned)tmp[7] << 16);
        *(uint4*)(gT + ((size_t)(b * LL + l0 + r)) * HH + h0 + c8) = o;
    }
}

// ---------------------------------------------------------------------------
// Kernel 4: out[b,o,l] = sum_i Wb[o,i] * gT[b,l,i] + bias[o]
// 128x128 tile, BK=64, 4 waves (2x2), 16x16x32 bf16 MFMA, global_load_lds.
// ---------------------------------------------------------------------------
__global__ __launch_bounds__(256) void out_gemm_mfma(
    const __hip_bfloat16* __restrict__ Wb,
    const __hip_bfloat16* __restrict__ gT,
    const float* __restrict__ bias,
    float* __restrict__ out)
{
    __shared__ __hip_bfloat16 As[128 * 64];   // [o 128][i 64]
    __shared__ __hip_bfloat16 Bs[128 * 64];   // [l 128][i 64]

    const int tid  = threadIdx.x;
    const int lane = tid & 63;
    const int wave = tid >> 6;
    const int wr = wave >> 1, wc = wave & 1;
    const int b  = blockIdx.z;
    const int o0 = blockIdx.x * 128;
    const int l0 = blockIdx.y * 128;

    const int srow = tid >> 3;            // 0..31 (row within 32-row chunk)
    const int scol = (tid & 7) * 8;       // element col within 64

    f32x4 acc[4][4] = {};

    for (int kt = 0; kt < 16; ++kt) {
        const int k0 = kt * 64;
        __syncthreads();                  // previous tile's compute done
        #pragma unroll
        for (int c = 0; c < 4; ++c) {
            int row = c * 32 + srow;
            const __hip_bfloat16* ga = Wb + (size_t)(o0 + row) * HH + k0 + scol;
            const __hip_bfloat16* gb = gT + ((size_t)(b * LL + l0 + row)) * HH + k0 + scol;
            __builtin_amdgcn_global_load_lds(
                (const __attribute__((address_space(1))) void*)ga,
                (__attribute__((address_space(3))) void*)(As + c * 2048 + wave * 512),
                16, 0, 0);
            __builtin_amdgcn_global_load_lds(
                (const __attribute__((address_space(1))) void*)gb,
                (__attribute__((address_space(3))) void*)(Bs + c * 2048 + wave * 512),
                16, 0, 0);
        }
        asm volatile("s_waitcnt vmcnt(0)" ::: "memory");
        __syncthreads();

        const int rA = wr * 64 + (lane & 15);
        const int rB = wc * 64 + (lane & 15);
        const int kf = (lane >> 4) * 8;
        bf16x8 af[4][2], bfr[4][2];
        #pragma unroll
        for (int m = 0; m < 4; ++m)
            #pragma unroll
            for (int ks = 0; ks < 2; ++ks)
                af[m][ks] = *(const bf16x8*)(As + (rA + m * 16) * 64 + ks * 32 + kf);
        #pragma unroll
        for (int n = 0; n < 4; ++n)
            #pragma unroll
            for (int ks = 0; ks < 2; ++ks)
                bfr[n][ks] = *(const bf16x8*)(Bs + (rB + n * 16) * 64 + ks * 32 + kf);
        #pragma unroll
        for (int m = 0; m < 4; ++m)
            #pragma unroll
            for (int n = 0; n < 4; ++n)
                #pragma unroll
                for (int ks = 0; ks < 2; ++ks)
                    acc[m][n] = __builtin_amdgcn_mfma_f32_16x16x32_bf16(
                        af[m][ks], bfr[n][ks], acc[m][n], 0, 0, 0);
    }

    #pragma unroll
    for (int m = 0; m < 4; ++m) {
        int obase = o0 + wr * 64 + m * 16 + (lane >> 4) * 4;
        #pragma unroll
        for (int n = 0; n < 4; ++n) {
            int l_ = l0 + wc * 64 + n * 16 + (lane & 15);
            #pragma unroll
            for (int r = 0; r < 4; ++r) {
                int o = obase + r;
                out[((size_t)(b * HH + o)) * LL + l_] = acc[m][n][r] + bias[o];
            }
        }
    }
}

extern "C" void kernel_launch(void* const* d_in, const int* in_sizes, int n_in,
                              void* d_out, int out_size, void* d_ws, size_t ws_size,
                              hipStream_t stream) {
    const float* u          = (const float*)d_in[0];
    const float* log_dt     = (const float*)d_in[1];
    const float* log_w_real = (const float*)d_in[2];
    const float* w_imag     = (const float*)d_in[3];
    const float* C_re       = (const float*)d_in[4];
    const float* C_im       = (const float*)d_in[5];
    const float* Dp         = (const float*)d_in[6];
    const float* W          = (const float*)d_in[7];
    const float* bias       = (const float*)d_in[8];
    float* out = (float*)d_out;

    // g (B,H,L) bf16 stashed in d_out's slack (33.5MB < 64MB); overwritten by GEMM later.
    __hip_bfloat16* g  = (__hip_bfloat16*)d_out;
    __hip_bfloat16* gT = (__hip_bfloat16*)d_ws;                         // 33.5 MB
    __hip_bfloat16* Wb = (__hip_bfloat16*)((char*)d_ws + 33554432);     // 2 MB

    conv_w<<<dim3(HH * HH / 1024), 256, 0, stream>>>(W, Wb);
    ssm_kernel<<<dim3(BB * HH), 256, 0, stream>>>(u, log_dt, log_w_real, w_imag,
                                                  C_re, C_im, Dp, g);
    transpose_g<<<dim3(HH / 64, LL / 64, BB), 256, 0, stream>>>(g, gT);
    out_gemm_mfma<<<dim3(HH / 128, LL / 128, BB), 256, 0, stream>>>(Wb, gT, bias, out);
}

// Round 3
// 155.983 us; speedup vs baseline: 6.2830x; 2.7157x over previous
//
#include <hip/hip_runtime.h>
#include <hip/hip_bf16.h>

#define HH 1024
#define LL 2048
#define BB 8
#define NN2 32     // complex modes
#define CT 128     // chunk size
#define NCH 16     // LL / CT

typedef short bf16x8 __attribute__((ext_vector_type(8)));
typedef float f32x4  __attribute__((ext_vector_type(4)));

static __device__ __forceinline__ unsigned short bfbits(float x) {
    __hip_bfloat16 h = __float2bfloat16(x);
    return *(unsigned short*)&h;
}
static __device__ __forceinline__ float f_from_bits(unsigned short b) {
    __hip_bfloat16 h; *(unsigned short*)&h = b; return __bfloat162float(h);
}

// LDS pool offsets (bytes)
#define OFF_U    0        // ushort U[128][128]   (32768)  rows bc=b*16+c, cols j
#define OFF_UN   32768    // union 16KB: AJ[64][128] -> K[128][64] -> AP[128][64]
#define OFF_P    49152    // ushort P/CS[128][64] (16384)
#define OFF_KT   65536    // float kt[128]        (512)
#define OFF_DTA  66048    // float2 dtA[32]       (256)
#define OFF_CN   66304    // float2 Cn[32]        (256)
#define LDS_TOT  66560

#define SWZ(off, row) ((off) ^ (((row) & 7) << 4))

// ---------------------------------------------------------------------------
// Kernel 1: one block per h. All 8 batches. MFMA chunked-scan SSM + GELU.
// ---------------------------------------------------------------------------
__global__ __launch_bounds__(512, 4) void ssm_mfma(
    const float* __restrict__ u, const float* __restrict__ log_dt,
    const float* __restrict__ log_w_real, const float* __restrict__ w_imag,
    const float* __restrict__ C_re, const float* __restrict__ C_im,
    const float* __restrict__ Dp, __hip_bfloat16* __restrict__ g_out)
{
    extern __shared__ char smem[];
    float2* dtA = (float2*)(smem + OFF_DTA);
    float2* Cn  = (float2*)(smem + OFF_CN);
    float*  kt  = (float*)(smem + OFF_KT);

    const int tid  = threadIdx.x;
    const int lane = tid & 63;
    const int wave = tid >> 6;
    const int wr4  = wave >> 1;     // 0..3 : 32 output rows each
    const int wc2  = wave & 1;      // 0..1 : 64 output cols each
    const int h    = blockIdx.x;

    // ---------------- ph0a: issue u loads; compute per-mode constants -------
    float4 ureg[8];
    #pragma unroll
    for (int q = 0; q < 8; ++q) {
        int flat = q * 512 + tid;           // float4 index
        int b = flat >> 9, c4 = flat & 511;
        ureg[q] = *(const float4*)(u + ((size_t)(b * HH + h)) * LL + c4 * 4);
    }
    if (tid < NN2) {
        int n = tid;
        float dt = expf(log_dt[h]);
        float wr = -expf(log_w_real[n]);
        float wi = w_imag[n];
        float dar = wr * dt, dai = wi * dt;
        dtA[n] = make_float2(dar, dai);
        float er = expf(dar);
        float sn, cs; sincosf(dai, &sn, &cs);
        float exr = er * cs - 1.0f, exi = er * sn;
        float den = wr * wr + wi * wi;
        float fr = (exr * wr + exi * wi) / den;
        float fi = (exi * wr - exr * wi) / den;
        float cre = C_re[h * NN2 + n], cim = C_im[h * NN2 + n];
        Cn[n] = make_float2(cre * fr - cim * fi, cre * fi + cim * fr);
    }
    if (tid < CT) kt[tid] = 0.0f;
    __syncthreads();

    // ---------------- ph0b: U bf16, AJ table, k-taps ------------------------
    #pragma unroll
    for (int q = 0; q < 8; ++q) {
        int flat = q * 512 + tid;
        int b = flat >> 9, c4 = flat & 511;
        int row = b * 16 + (c4 >> 5);
        int j   = (c4 & 31) * 4;
        ushort4 o;
        o.x = bfbits(ureg[q].x); o.y = bfbits(ureg[q].y);
        o.z = bfbits(ureg[q].z); o.w = bfbits(ureg[q].w);
        *(ushort4*)(smem + SWZ(OFF_U + row * 256 + j * 2, row)) = o;
    }
    // AJ[n'][j] : n' rows 2n (re), 2n+1 (im); value a^(127-j)
    #pragma unroll
    for (int q = 0; q < 8; ++q) {
        int idx = q * 512 + tid;            // 4096 (n,j) tasks
        int n = idx >> 7, j = idx & 127;
        float p = (float)(127 - j);
        float2 dA = dtA[n];
        float mag = expf(dA.x * p);
        float sn, cs; sincosf(dA.y * p, &sn, &cs);
        int r0 = 2 * n, r1 = 2 * n + 1;
        *(unsigned short*)(smem + SWZ(OFF_UN + r0 * 256 + j * 2, r0)) = bfbits(mag * cs);
        *(unsigned short*)(smem + SWZ(OFF_UN + r1 * 256 + j * 2, r1)) = bfbits(mag * sn);
    }
    // k-taps: kt[t] = 2 Re sum_n Cn a^t  (atomic partial sums)
    #pragma unroll
    for (int q = 0; q < 8; ++q) {
        int idx = q * 512 + tid;            // 4096 (t,n) tasks
        int t = idx >> 5, n = idx & 31;
        float2 dA = dtA[n];
        float mag = expf(dA.x * (float)t);
        float sn, cs; sincosf(dA.y * (float)t, &sn, &cs);
        float2 C = Cn[n];
        atomicAdd(&kt[t], 2.0f * (C.x * (mag * cs) - C.y * (mag * sn)));
    }
    __syncthreads();

    // ---------------- ph1: partials GEMM  P[bc][n'] = U x AJ ----------------
    f32x4 accP[2][2] = {};
    #pragma unroll
    for (int ks = 0; ks < 4; ++ks) {
        int kf = ks * 32 + (lane >> 4) * 8;
        bf16x8 a0, a1, b0, b1;
        {
            int r = wr4 * 32 + (lane & 15);
            a0 = *(bf16x8*)(smem + SWZ(OFF_U + r * 256 + kf * 2, r));
            int r2 = r + 16;
            a1 = *(bf16x8*)(smem + SWZ(OFF_U + r2 * 256 + kf * 2, r2));
        }
        {
            int r = wc2 * 32 + (lane & 15);
            b0 = *(bf16x8*)(smem + SWZ(OFF_UN + r * 256 + kf * 2, r));
            int r2 = r + 16;
            b1 = *(bf16x8*)(smem + SWZ(OFF_UN + r2 * 256 + kf * 2, r2));
        }
        accP[0][0] = __builtin_amdgcn_mfma_f32_16x16x32_bf16(a0, b0, accP[0][0], 0, 0, 0);
        accP[0][1] = __builtin_amdgcn_mfma_f32_16x16x32_bf16(a0, b1, accP[0][1], 0, 0, 0);
        accP[1][0] = __builtin_amdgcn_mfma_f32_16x16x32_bf16(a1, b0, accP[1][0], 0, 0, 0);
        accP[1][1] = __builtin_amdgcn_mfma_f32_16x16x32_bf16(a1, b1, accP[1][1], 0, 0, 0);
    }
    __syncthreads();   // all AJ reads done (region reused for K later)
    #pragma unroll
    for (int mt = 0; mt < 2; ++mt)
        #pragma unroll
        for (int nt = 0; nt < 2; ++nt)
            #pragma unroll
            for (int r = 0; r < 4; ++r) {
                int row = wr4 * 32 + mt * 16 + (lane >> 4) * 4 + r;
                int col = wc2 * 32 + nt * 16 + (lane & 15);
                *(unsigned short*)(smem + SWZ(OFF_P + row * 128 + col * 2, row)) =
                    bfbits(accP[mt][nt][r]);
            }
    __syncthreads();

    // ---------------- ph2: scan (tid<256) + K1 build (all) ------------------
    // K1[tt][j] j in [0,64)
    #pragma unroll
    for (int q = 0; q < 16; ++q) {
        int idx = q * 512 + tid;            // 8192 entries
        int ttr = idx >> 6, j = idx & 63;
        float val = (ttr >= j) ? kt[ttr - j] : 0.0f;
        *(unsigned short*)(smem + SWZ(OFF_UN + ttr * 128 + j * 2, ttr)) = bfbits(val);
    }
    if (tid < 256) {
        int b = tid >> 5, n = tid & 31;
        float2 C = Cn[n];
        float2 dA = dtA[n];
        float magA = expf(dA.x * 128.0f);
        float snA, csA; sincosf(dA.y * 128.0f, &snA, &csA);
        float2 A = make_float2(magA * csA, magA * snA);
        float sr = 0.f, si = 0.f;
        for (int c = 0; c < NCH; ++c) {
            int row = b * 16 + c;
            int off = SWZ(OFF_P + row * 128 + n * 4, row);
            unsigned int pv = *(unsigned int*)(smem + off);
            float pr = f_from_bits((unsigned short)(pv & 0xffff));
            float pi = f_from_bits((unsigned short)(pv >> 16));
            float csr = C.x * sr - C.y * si;
            float csi = C.x * si + C.y * sr;
            *(unsigned int*)(smem + off) =
                (unsigned)bfbits(csr) | ((unsigned)bfbits(csi) << 16);
            float nsr = A.x * sr - A.y * si + pr;
            float nsi = A.x * si + A.y * sr + pi;
            sr = nsr; si = nsi;
        }
    }
    __syncthreads();

    // ---------------- ph3a: conv GEMM half 1 (j in [0,64)) ------------------
    f32x4 acc[2][4] = {};
    #pragma unroll
    for (int ks = 0; ks < 2; ++ks) {
        int kf = ks * 32 + (lane >> 4) * 8;
        bf16x8 a0, a1, bv[4];
        {
            int r = wr4 * 32 + (lane & 15);
            a0 = *(bf16x8*)(smem + SWZ(OFF_U + r * 256 + kf * 2, r));
            int r2 = r + 16;
            a1 = *(bf16x8*)(smem + SWZ(OFF_U + r2 * 256 + kf * 2, r2));
        }
        #pragma unroll
        for (int nt = 0; nt < 4; ++nt) {
            int ttr = wc2 * 64 + nt * 16 + (lane & 15);
            bv[nt] = *(bf16x8*)(smem + SWZ(OFF_UN + ttr * 128 + kf * 2, ttr));
        }
        #pragma unroll
        for (int nt = 0; nt < 4; ++nt) {
            acc[0][nt] = __builtin_amdgcn_mfma_f32_16x16x32_bf16(a0, bv[nt], acc[0][nt], 0, 0, 0);
            acc[1][nt] = __builtin_amdgcn_mfma_f32_16x16x32_bf16(a1, bv[nt], acc[1][nt], 0, 0, 0);
        }
    }
    __syncthreads();   // K1 consumed

    // ---------------- ph3b: K2 build + conv GEMM half 2 ---------------------
    #pragma unroll
    for (int q = 0; q < 16; ++q) {
        int idx = q * 512 + tid;
        int ttr = idx >> 6, j = idx & 63;
        float val = (ttr >= 64 + j) ? kt[ttr - 64 - j] : 0.0f;
        *(unsigned short*)(smem + SWZ(OFF_UN + ttr * 128 + j * 2, ttr)) = bfbits(val);
    }
    __syncthreads();
    #pragma unroll
    for (int ks = 0; ks < 2; ++ks) {
        int kf = ks * 32 + (lane >> 4) * 8;
        bf16x8 a0, a1, bv[4];
        {
            int r = wr4 * 32 + (lane & 15);
            a0 = *(bf16x8*)(smem + SWZ(OFF_U + r * 256 + 128 + kf * 2, r));
            int r2 = r + 16;
            a1 = *(bf16x8*)(smem + SWZ(OFF_U + r2 * 256 + 128 + kf * 2, r2));
        }
        #pragma unroll
        for (int nt = 0; nt < 4; ++nt) {
            int ttr = wc2 * 64 + nt * 16 + (lane & 15);
            bv[nt] = *(bf16x8*)(smem + SWZ(OFF_UN + ttr * 128 + kf * 2, ttr));
        }
        #pragma unroll
        for (int nt = 0; nt < 4; ++nt) {
            acc[0][nt] = __builtin_amdgcn_mfma_f32_16x16x32_bf16(a0, bv[nt], acc[0][nt], 0, 0, 0);
            acc[1][nt] = __builtin_amdgcn_mfma_f32_16x16x32_bf16(a1, bv[nt], acc[1][nt], 0, 0, 0);
        }
    }
    __syncthreads();   // K2 consumed

    // ---------------- ph4: AP build + state GEMM ----------------------------
    // AP[tt][2n] = 2 Re a^(tt+1), AP[tt][2n+1] = -2 Im a^(tt+1)
    #pragma unroll
    for (int q = 0; q < 8; ++q) {
        int idx = q * 512 + tid;            // 4096 (n,tt) tasks
        int n = idx >> 7, ttr = idx & 127;
        float p = (float)(ttr + 1);
        float2 dA = dtA[n];
        float mag = expf(dA.x * p);
        float sn, cs; sincosf(dA.y * p, &sn, &cs);
        int off = SWZ(OFF_UN + ttr * 128 + n * 4, ttr);
        *(unsigned int*)(smem + off) =
            (unsigned)bfbits(2.0f * mag * cs) | ((unsigned)bfbits(-2.0f * mag * sn) << 16);
    }
    __syncthreads();
    #pragma unroll
    for (int ks = 0; ks < 2; ++ks) {
        int kf = ks * 32 + (lane >> 4) * 8;
        bf16x8 a0, a1, bv[4];
        {
            int r = wr4 * 32 + (lane & 15);
            a0 = *(bf16x8*)(smem + SWZ(OFF_P + r * 128 + kf * 2, r));
            int r2 = r + 16;
            a1 = *(bf16x8*)(smem + SWZ(OFF_P + r2 * 128 + kf * 2, r2));
        }
        #pragma unroll
        for (int nt = 0; nt < 4; ++nt) {
            int ttr = wc2 * 64 + nt * 16 + (lane & 15);
            bv[nt] = *(bf16x8*)(smem + SWZ(OFF_UN + ttr * 128 + kf * 2, ttr));
        }
        #pragma unroll
        for (int nt = 0; nt < 4; ++nt) {
            acc[0][nt] = __builtin_amdgcn_mfma_f32_16x16x32_bf16(a0, bv[nt], acc[0][nt], 0, 0, 0);
            acc[1][nt] = __builtin_amdgcn_mfma_f32_16x16x32_bf16(a1, bv[nt], acc[1][nt], 0, 0, 0);
        }
    }

    // ---------------- ph5: epilogue  y = acc + D*u, GELU, store bf16 --------
    const float Dv = Dp[h];
    #pragma unroll
    for (int mt = 0; mt < 2; ++mt)
        #pragma unroll
        for (int nt = 0; nt < 4; ++nt)
            #pragma unroll
            for (int r = 0; r < 4; ++r) {
                int row = wr4 * 32 + mt * 16 + (lane >> 4) * 4 + r;
                int ttr = wc2 * 64 + nt * 16 + (lane & 15);
                int b = row >> 4, c = row & 15;
                float uv = f_from_bits(*(unsigned short*)(smem + SWZ(OFF_U + row * 256 + ttr * 2, row)));
                float y = acc[mt][nt][r] + Dv * uv;
                float gel = 0.5f * y * (1.0f + erff(y * 0.70710678118f));
                g_out[((size_t)(b * HH + h)) * LL + c * CT + ttr] = __float2bfloat16(gel);
            }
}

// ---------------------------------------------------------------------------
// Kernel 2: W (1024x1024 fp32) -> bf16
// ---------------------------------------------------------------------------
__global__ __launch_bounds__(256) void conv_w(
    const float* __restrict__ W, __hip_bfloat16* __restrict__ Wb)
{
    int i = blockIdx.x * 256 + threadIdx.x;
    float4 v = ((const float4*)W)[i];
    ushort4 o;
    o.x = bfbits(v.x); o.y = bfbits(v.y); o.z = bfbits(v.z); o.w = bfbits(v.w);
    ((ushort4*)Wb)[i] = o;
}

// ---------------------------------------------------------------------------
// Kernel 3: transpose g (B,H,L) bf16 -> gT (B,L,H) bf16
// ---------------------------------------------------------------------------
__global__ __launch_bounds__(256) void transpose_g(
    const __hip_bfloat16* __restrict__ g, __hip_bfloat16* __restrict__ gT)
{
    __shared__ __hip_bfloat16 t[64][66];
    const int tid = threadIdx.x;
    const int b  = blockIdx.z;
    const int h0 = blockIdx.x * 64;
    const int l0 = blockIdx.y * 64;

    #pragma unroll
    for (int q = 0; q < 2; ++q) {
        int idx = tid + q * 256;
        int r = idx >> 3, c8 = (idx & 7) * 8;
        uint4 v = *(const uint4*)(g + ((size_t)(b * HH + h0 + r)) * LL + l0 + c8);
        unsigned int* dst = (unsigned int*)&t[r][c8];
        dst[0] = v.x; dst[1] = v.y; dst[2] = v.z; dst[3] = v.w;
    }
    __syncthreads();
    #pragma unroll
    for (int q = 0; q < 2; ++q) {
        int idx = tid + q * 256;
        int r = idx >> 3, c8 = (idx & 7) * 8;
        unsigned short tmp[8];
        #pragma unroll
        for (int j = 0; j < 8; ++j) tmp[j] = *(unsigned short*)&t[c8 + j][r];
        uint4 o;
        o.x = (unsigned)tmp[0] | ((unsigned)tmp[1] << 16);
        o.y = (unsigned)tmp[2] | ((unsigned)tmp[3] << 16);
        o.z = (unsigned)tmp[4] | ((unsigned)tmp[5] << 16);
        o.w = (unsigned)tmp[6] | ((unsigned)tmp[7] << 16);
        *(uint4*)(gT + ((size_t)(b * LL + l0 + r)) * HH + h0 + c8) = o;
    }
}

// ---------------------------------------------------------------------------
// Kernel 4: out[b,o,l] = sum_i Wb[o,i] * gT[b,l,i] + bias[o]
// ---------------------------------------------------------------------------
__global__ __launch_bounds__(256) void out_gemm_mfma(
    const __hip_bfloat16* __restrict__ Wb,
    const __hip_bfloat16* __restrict__ gT,
    const float* __restrict__ bias,
    float* __restrict__ out)
{
    __shared__ __hip_bfloat16 As[128 * 64];
    __shared__ __hip_bfloat16 Bs[128 * 64];

    const int tid  = threadIdx.x;
    const int lane = tid & 63;
    const int wave = tid >> 6;
    const int wr = wave >> 1, wc = wave & 1;
    const int b  = blockIdx.z;
    const int o0 = blockIdx.x * 128;
    const int l0 = blockIdx.y * 128;

    const int srow = tid >> 3;
    const int scol = (tid & 7) * 8;

    f32x4 acc[4][4] = {};

    for (int kt = 0; kt < 16; ++kt) {
        const int k0 = kt * 64;
        __syncthreads();
        #pragma unroll
        for (int c = 0; c < 4; ++c) {
            int row = c * 32 + srow;
            const __hip_bfloat16* ga = Wb + (size_t)(o0 + row) * HH + k0 + scol;
            const __hip_bfloat16* gb = gT + ((size_t)(b * LL + l0 + row)) * HH + k0 + scol;
            __builtin_amdgcn_global_load_lds(
                (const __attribute__((address_space(1))) void*)ga,
                (__attribute__((address_space(3))) void*)(As + c * 2048 + wave * 512),
                16, 0, 0);
            __builtin_amdgcn_global_load_lds(
                (const __attribute__((address_space(1))) void*)gb,
                (__attribute__((address_space(3))) void*)(Bs + c * 2048 + wave * 512),
                16, 0, 0);
        }
        asm volatile("s_waitcnt vmcnt(0)" ::: "memory");
        __syncthreads();

        const int rA = wr * 64 + (lane & 15);
        const int rB = wc * 64 + (lane & 15);
        const int kf = (lane >> 4) * 8;
        bf16x8 af[4][2], bfr[4][2];
        #pragma unroll
        for (int m = 0; m < 4; ++m)
            #pragma unroll
            for (int ks = 0; ks < 2; ++ks)
                af[m][ks] = *(const bf16x8*)(As + (rA + m * 16) * 64 + ks * 32 + kf);
        #pragma unroll
        for (int n = 0; n < 4; ++n)
            #pragma unroll
            for (int ks = 0; ks < 2; ++ks)
                bfr[n][ks] = *(const bf16x8*)(Bs + (rB + n * 16) * 64 + ks * 32 + kf);
        #pragma unroll
        for (int m = 0; m < 4; ++m)
            #pragma unroll
            for (int n = 0; n < 4; ++n)
                #pragma unroll
                for (int ks = 0; ks < 2; ++ks)
                    acc[m][n] = __builtin_amdgcn_mfma_f32_16x16x32_bf16(
                        af[m][ks], bfr[n][ks], acc[m][n], 0, 0, 0);
    }

    #pragma unroll
    for (int m = 0; m < 4; ++m) {
        int obase = o0 + wr * 64 + m * 16 + (lane >> 4) * 4;
        #pragma unroll
        for (int n = 0; n < 4; ++n) {
            int l_ = l0 + wc * 64 + n * 16 + (lane & 15);
            #pragma unroll
            for (int r = 0; r < 4; ++r) {
                int o = obase + r;
                out[((size_t)(b * HH + o)) * LL + l_] = acc[m][n][r] + bias[o];
            }
        }
    }
}

extern "C" void kernel_launch(void* const* d_in, const int* in_sizes, int n_in,
                              void* d_out, int out_size, void* d_ws, size_t ws_size,
                              hipStream_t stream) {
    const float* u          = (const float*)d_in[0];
    const float* log_dt     = (const float*)d_in[1];
    const float* log_w_real = (const float*)d_in[2];
    const float* w_imag     = (const float*)d_in[3];
    const float* C_re       = (const float*)d_in[4];
    const float* C_im       = (const float*)d_in[5];
    const float* Dp         = (const float*)d_in[6];
    const float* W          = (const float*)d_in[7];
    const float* bias       = (const float*)d_in[8];
    float* out = (float*)d_out;

    __hip_bfloat16* g  = (__hip_bfloat16*)d_out;                        // stash in d_out slack
    __hip_bfloat16* gT = (__hip_bfloat16*)d_ws;                         // 33.5 MB
    __hip_bfloat16* Wb = (__hip_bfloat16*)((char*)d_ws + 33554432);     // 2 MB

    hipFuncSetAttribute((const void*)ssm_mfma,
                        hipFuncAttributeMaxDynamicSharedMemorySize, LDS_TOT);

    conv_w<<<dim3(HH * HH / 1024), 256, 0, stream>>>(W, Wb);
    ssm_mfma<<<dim3(HH), 512, LDS_TOT, stream>>>(u, log_dt, log_w_real, w_imag,
                                                 C_re, C_im, Dp, g);
    transpose_g<<<dim3(HH / 64, LL / 64, BB), 256, 0, stream>>>(g, gT);
    out_gemm_mfma<<<dim3(HH / 128, LL / 128, BB), 256, 0, stream>>>(Wb, gT, bias, out);
}

// Round 5
// 126.018 us; speedup vs baseline: 7.7770x; 1.2378x over previous
//
#include <hip/hip_runtime.h>
#include <hip/hip_bf16.h>

#define HH 1024
#define LL 2048
#define BB 8
#define NN2 32     // complex modes
#define CT 128     // chunk size
#define NCH 16     // LL / CT

typedef short bf16x8 __attribute__((ext_vector_type(8)));
typedef float f32x4  __attribute__((ext_vector_type(4)));

static __device__ __forceinline__ unsigned short bfbits(float x) {
    __hip_bfloat16 h = __float2bfloat16(x);
    return *(unsigned short*)&h;
}
static __device__ __forceinline__ float f_from_bits(unsigned short b) {
    __hip_bfloat16 h; *(unsigned short*)&h = b; return __bfloat162float(h);
}
static __device__ __forceinline__ float2 cmul(float2 a, float2 b) {
    return make_float2(fmaf(-a.y, b.y, a.x * b.x), fmaf(a.y, b.x, a.x * b.y));
}

// LDS pool offsets (bytes)
#define OFF_U    0        // ushort U[128][128]   (32768)  rows bc=b*16+c, cols j
#define OFF_UN   32768    // union 16KB: AJ[64][128] -> K1/K2[128][64] -> AP[128][64]
#define OFF_P    49152    // ushort P/CS[128][64] (16384)
#define OFF_KT   65536    // float kt[128]        (512)
#define OFF_DTA  66048    // float2 dtA[32]       (256)
#define OFF_CN   66304    // float2 Cn[32]        (256)
#define OFF_LO   66560    // float2 lo[32][8]     (2048)   a^j, j=0..7
#define OFF_HI   68608    // float2 hi[32][17]    (4352)   a^(8j), j=0..16
#define LDS_TOT  72960

#define SWZ(off, row) ((off) ^ (((row) & 7) << 4))

// ---------------------------------------------------------------------------
// Kernel 1: one block per h. All 8 batches. MFMA chunked-scan SSM + GELU.
// ---------------------------------------------------------------------------
__global__ __launch_bounds__(512, 4) void ssm_mfma(
    const float* __restrict__ u, const float* __restrict__ log_dt,
    const float* __restrict__ log_w_real, const float* __restrict__ w_imag,
    const float* __restrict__ C_re, const float* __restrict__ C_im,
    const float* __restrict__ Dp, __hip_bfloat16* __restrict__ g_out)
{
    extern __shared__ char smem[];
    float2* dtA = (float2*)(smem + OFF_DTA);
    float2* Cn  = (float2*)(smem + OFF_CN);
    float*  kt  = (float*)(smem + OFF_KT);
    float2* lo  = (float2*)(smem + OFF_LO);
    float2* hi  = (float2*)(smem + OFF_HI);

    const int tid  = threadIdx.x;
    const int lane = tid & 63;
    const int wave = tid >> 6;
    const int wr4  = wave >> 1;     // 0..3 : 32 output rows each
    const int wc2  = wave & 1;      // 0..1 : 64 output cols each
    const int h    = blockIdx.x;

    // ---------------- ph0a: issue u loads; per-mode constants ---------------
    float4 ureg[8];
    #pragma unroll
    for (int q = 0; q < 8; ++q) {
        int b = q, c4 = tid;
        ureg[q] = *(const float4*)(u + ((size_t)(b * HH + h)) * LL + c4 * 4);
    }
    if (tid < NN2) {
        int n = tid;
        float dt = expf(log_dt[h]);
        float wr = -expf(log_w_real[n]);
        float wi = w_imag[n];
        float dar = wr * dt, dai = wi * dt;
        dtA[n] = make_float2(dar, dai);
        float er = expf(dar);
        float sn, cs; sincosf(dai, &sn, &cs);
        float exr = er * cs - 1.0f, exi = er * sn;
        float den = wr * wr + wi * wi;
        float fr = (exr * wr + exi * wi) / den;
        float fi = (exi * wr - exr * wi) / den;
        float cre = C_re[h * NN2 + n], cim = C_im[h * NN2 + n];
        Cn[n] = make_float2(cre * fr - cim * fi, cre * fi + cim * fr);
    }
    __syncthreads();

    // ---------------- ph0b: U bf16 write + power tables lo/hi ---------------
    #pragma unroll
    for (int q = 0; q < 8; ++q) {
        int row = q * 16 + (tid >> 5);
        int j   = (tid & 31) * 4;
        ushort4 o;
        o.x = bfbits(ureg[q].x); o.y = bfbits(ureg[q].y);
        o.z = bfbits(ureg[q].z); o.w = bfbits(ureg[q].w);
        *(ushort4*)(smem + SWZ(OFF_U + row * 256 + j * 2, row)) = o;
    }
    // 800 table entries, 512 threads -> grid-stride (BUGFIX vs R4: tid<800 never
    // ran for tid>=512, leaving hi[] garbage -> NaN).
    for (int idx = tid; idx < 800; idx += 512) {
        int n, j, p;
        if (idx < 256) { n = idx >> 3; j = idx & 7; p = j; }
        else { int k = idx - 256; n = (k * 241) >> 12; j = k - n * 17; p = j << 3; }
        float2 dA = dtA[n];
        float mag = expf(dA.x * (float)p);
        float sn, cs; sincosf(dA.y * (float)p, &sn, &cs);
        float2 v = make_float2(mag * cs, mag * sn);
        if (idx < 256) lo[n * 8 + j] = v; else hi[n * 17 + j] = v;
    }
    __syncthreads();

    // ---------------- ph0c: AJ table + k-taps (via composed powers) ---------
    // AJ rows 2n (re), 2n+1 (im); AJ[.][j] = a^(127-j)
    #pragma unroll
    for (int q = 0; q < 2; ++q) {
        int vidx = q * 512 + tid;           // 1024 tasks of 4 cols
        int n = vidx >> 5, j0 = (vidx & 31) * 4;
        float2 a0, a1, a2, a3;
        {
            int p = 127 - j0;       a0 = cmul(lo[n * 8 + (p & 7)], hi[n * 17 + (p >> 3)]);
            p = 126 - j0;           a1 = cmul(lo[n * 8 + (p & 7)], hi[n * 17 + (p >> 3)]);
            p = 125 - j0;           a2 = cmul(lo[n * 8 + (p & 7)], hi[n * 17 + (p >> 3)]);
            p = 124 - j0;           a3 = cmul(lo[n * 8 + (p & 7)], hi[n * 17 + (p >> 3)]);
        }
        ushort4 re, im;
        re.x = bfbits(a0.x); re.y = bfbits(a1.x); re.z = bfbits(a2.x); re.w = bfbits(a3.x);
        im.x = bfbits(a0.y); im.y = bfbits(a1.y); im.z = bfbits(a2.y); im.w = bfbits(a3.y);
        int r0 = 2 * n, r1 = 2 * n + 1;
        *(ushort4*)(smem + SWZ(OFF_UN + r0 * 256 + j0 * 2, r0)) = re;
        *(ushort4*)(smem + SWZ(OFF_UN + r1 * 256 + j0 * 2, r1)) = im;
    }
    {   // kt[t] = 2 Re sum_n Cn a^t : quad per tap, shfl reduce
        int t = tid >> 2, nb = (tid & 3) * 8;
        float s = 0.f;
        #pragma unroll
        for (int i = 0; i < 8; ++i) {
            int n = nb + i;
            float2 a = cmul(lo[n * 8 + (t & 7)], hi[n * 17 + (t >> 3)]);
            float2 C = Cn[n];
            s += C.x * a.x - C.y * a.y;
        }
        s += __shfl_xor(s, 1);
        s += __shfl_xor(s, 2);
        if ((tid & 3) == 0) kt[t] = 2.0f * s;
    }
    __syncthreads();

    // ---------------- ph1: partials GEMM  P[bc][n'] = U x AJ ----------------
    f32x4 accP[2][2] = {};
    #pragma unroll
    for (int ks = 0; ks < 4; ++ks) {
        int kf = ks * 32 + (lane >> 4) * 8;
        bf16x8 a0, a1, b0, b1;
        {
            int r = wr4 * 32 + (lane & 15);
            a0 = *(bf16x8*)(smem + SWZ(OFF_U + r * 256 + kf * 2, r));
            int r2 = r + 16;
            a1 = *(bf16x8*)(smem + SWZ(OFF_U + r2 * 256 + kf * 2, r2));
        }
        {
            int r = wc2 * 32 + (lane & 15);
            b0 = *(bf16x8*)(smem + SWZ(OFF_UN + r * 256 + kf * 2, r));
            int r2 = r + 16;
            b1 = *(bf16x8*)(smem + SWZ(OFF_UN + r2 * 256 + kf * 2, r2));
        }
        accP[0][0] = __builtin_amdgcn_mfma_f32_16x16x32_bf16(a0, b0, accP[0][0], 0, 0, 0);
        accP[0][1] = __builtin_amdgcn_mfma_f32_16x16x32_bf16(a0, b1, accP[0][1], 0, 0, 0);
        accP[1][0] = __builtin_amdgcn_mfma_f32_16x16x32_bf16(a1, b0, accP[1][0], 0, 0, 0);
        accP[1][1] = __builtin_amdgcn_mfma_f32_16x16x32_bf16(a1, b1, accP[1][1], 0, 0, 0);
    }
    __syncthreads();   // all AJ reads done (region reused for K1)
    #pragma unroll
    for (int mt = 0; mt < 2; ++mt)
        #pragma unroll
        for (int nt = 0; nt < 2; ++nt)
            #pragma unroll
            for (int r = 0; r < 4; ++r) {
                int row = wr4 * 32 + mt * 16 + (lane >> 4) * 4 + r;
                int col = wc2 * 32 + nt * 16 + (lane & 15);
                *(unsigned short*)(smem + SWZ(OFF_P + row * 128 + col * 2, row)) =
                    bfbits(accP[mt][nt][r]);
            }
    __syncthreads();

    // ---------------- ph2: scan (tid<256) + K1 build (all) ------------------
    #pragma unroll
    for (int q = 0; q < 16; ++q) {
        int idx = q * 512 + tid;
        int ttr = idx >> 6, j = idx & 63;
        float val = (ttr >= j) ? kt[ttr - j] : 0.0f;
        *(unsigned short*)(smem + SWZ(OFF_UN + ttr * 128 + j * 2, ttr)) = bfbits(val);
    }
    if (tid < 256) {
        int b = tid >> 5, n = tid & 31;
        float2 C = Cn[n];
        float2 A = hi[n * 17 + 16];          // a^128
        float sr = 0.f, si = 0.f;
        for (int c = 0; c < NCH; ++c) {
            int row = b * 16 + c;
            int off = SWZ(OFF_P + row * 128 + n * 4, row);
            unsigned int pv = *(unsigned int*)(smem + off);
            float pr = f_from_bits((unsigned short)(pv & 0xffff));
            float pi = f_from_bits((unsigned short)(pv >> 16));
            float csr = C.x * sr - C.y * si;
            float csi = C.x * si + C.y * sr;
            *(unsigned int*)(smem + off) =
                (unsigned)bfbits(csr) | ((unsigned)bfbits(csi) << 16);
            float nsr = A.x * sr - A.y * si + pr;
            float nsi = A.x * si + A.y * sr + pi;
            sr = nsr; si = nsi;
        }
    }
    __syncthreads();

    // ---------------- ph3a: conv GEMM half 1 (j in [0,64)) ------------------
    f32x4 acc[2][4] = {};
    #pragma unroll
    for (int ks = 0; ks < 2; ++ks) {
        int kf = ks * 32 + (lane >> 4) * 8;
        bf16x8 a0, a1, bv[4];
        {
            int r = wr4 * 32 + (lane & 15);
            a0 = *(bf16x8*)(smem + SWZ(OFF_U + r * 256 + kf * 2, r));
            int r2 = r + 16;
            a1 = *(bf16x8*)(smem + SWZ(OFF_U + r2 * 256 + kf * 2, r2));
        }
        #pragma unroll
        for (int nt = 0; nt < 4; ++nt) {
            int ttr = wc2 * 64 + nt * 16 + (lane & 15);
            bv[nt] = *(bf16x8*)(smem + SWZ(OFF_UN + ttr * 128 + kf * 2, ttr));
        }
        #pragma unroll
        for (int nt = 0; nt < 4; ++nt) {
            acc[0][nt] = __builtin_amdgcn_mfma_f32_16x16x32_bf16(a0, bv[nt], acc[0][nt], 0, 0, 0);
            acc[1][nt] = __builtin_amdgcn_mfma_f32_16x16x32_bf16(a1, bv[nt], acc[1][nt], 0, 0, 0);
        }
    }
    __syncthreads();   // K1 consumed

    // ---------------- ph3b: K2 build + conv GEMM half 2 ---------------------
    #pragma unroll
    for (int q = 0; q < 16; ++q) {
        int idx = q * 512 + tid;
        int ttr = idx >> 6, j = idx & 63;
        float val = (ttr >= 64 + j) ? kt[ttr - 64 - j] : 0.0f;
        *(unsigned short*)(smem + SWZ(OFF_UN + ttr * 128 + j * 2, ttr)) = bfbits(val);
    }
    __syncthreads();
    #pragma unroll
    for (int ks = 0; ks < 2; ++ks) {
        int kf = ks * 32 + (lane >> 4) * 8;
        bf16x8 a0, a1, bv[4];
        {
            int r = wr4 * 32 + (lane & 15);
            a0 = *(bf16x8*)(smem + SWZ(OFF_U + r * 256 + 128 + kf * 2, r));
            int r2 = r + 16;
            a1 = *(bf16x8*)(smem + SWZ(OFF_U + r2 * 256 + 128 + kf * 2, r2));
        }
        #pragma unroll
        for (int nt = 0; nt < 4; ++nt) {
            int ttr = wc2 * 64 + nt * 16 + (lane & 15);
            bv[nt] = *(bf16x8*)(smem + SWZ(OFF_UN + ttr * 128 + kf * 2, ttr));
        }
        #pragma unroll
        for (int nt = 0; nt < 4; ++nt) {
            acc[0][nt] = __builtin_amdgcn_mfma_f32_16x16x32_bf16(a0, bv[nt], acc[0][nt], 0, 0, 0);
            acc[1][nt] = __builtin_amdgcn_mfma_f32_16x16x32_bf16(a1, bv[nt], acc[1][nt], 0, 0, 0);
        }
    }
    __syncthreads();   // K2 consumed

    // ---------------- ph4: AP build + state GEMM ----------------------------
    // AP[tt][2n] = 2 Re a^(tt+1), AP[tt][2n+1] = -2 Im a^(tt+1)
    #pragma unroll
    for (int q = 0; q < 8; ++q) {
        int idx = q * 512 + tid;
        int n = idx >> 7, ttr = idx & 127;
        int p = ttr + 1;
        float2 a = cmul(lo[n * 8 + (p & 7)], hi[n * 17 + (p >> 3)]);
        int off = SWZ(OFF_UN + ttr * 128 + n * 4, ttr);
        *(unsigned int*)(smem + off) =
            (unsigned)bfbits(2.0f * a.x) | ((unsigned)bfbits(-2.0f * a.y) << 16);
    }
    __syncthreads();
    #pragma unroll
    for (int ks = 0; ks < 2; ++ks) {
        int kf = ks * 32 + (lane >> 4) * 8;
        bf16x8 a0, a1, bv[4];
        {
            int r = wr4 * 32 + (lane & 15);
            a0 = *(bf16x8*)(smem + SWZ(OFF_P + r * 128 + kf * 2, r));
            int r2 = r + 16;
            a1 = *(bf16x8*)(smem + SWZ(OFF_P + r2 * 128 + kf * 2, r2));
        }
        #pragma unroll
        for (int nt = 0; nt < 4; ++nt) {
            int ttr = wc2 * 64 + nt * 16 + (lane & 15);
            bv[nt] = *(bf16x8*)(smem + SWZ(OFF_UN + ttr * 128 + kf * 2, ttr));
        }
        #pragma unroll
        for (int nt = 0; nt < 4; ++nt) {
            acc[0][nt] = __builtin_amdgcn_mfma_f32_16x16x32_bf16(a0, bv[nt], acc[0][nt], 0, 0, 0);
            acc[1][nt] = __builtin_amdgcn_mfma_f32_16x16x32_bf16(a1, bv[nt], acc[1][nt], 0, 0, 0);
        }
    }

    // ---------------- ph5: epilogue: y = acc + D*u, GELU -> LDS -> stores ---
    const float Dv = Dp[h];
    #pragma unroll
    for (int mt = 0; mt < 2; ++mt)
        #pragma unroll
        for (int nt = 0; nt < 4; ++nt)
            #pragma unroll
            for (int r = 0; r < 4; ++r) {
                int row = wr4 * 32 + mt * 16 + (lane >> 4) * 4 + r;
                int ttr = wc2 * 64 + nt * 16 + (lane & 15);
                int off = SWZ(OFF_U + row * 256 + ttr * 2, row);
                float uv = f_from_bits(*(unsigned short*)(smem + off));
                float y = acc[mt][nt][r] + Dv * uv;
                // fast GELU (tanh form, hw exp)
                float z = 0.7978845608f * (y + 0.044715f * y * y * y);
                float e = __expf(2.0f * z);
                float th = 1.0f - 2.0f / (e + 1.0f);
                float gel = 0.5f * y * (1.0f + th);
                *(unsigned short*)(smem + off) = bfbits(gel);   // owner-exclusive slot
            }
    __syncthreads();
    #pragma unroll
    for (int q = 0; q < 4; ++q) {
        int flat = q * 512 + tid;                // 2048 uint4 tiles
        int row = flat >> 4, c16 = flat & 15;
        uint4 v = *(uint4*)(smem + SWZ(OFF_U + row * 256 + c16 * 16, row));
        int b = row >> 4, c = row & 15;
        *(uint4*)(g_out + ((size_t)(b * HH + h)) * LL + c * CT + c16 * 8) = v;
    }
}

// ---------------------------------------------------------------------------
// Kernel 2: W (1024x1024 fp32) -> bf16
// ---------------------------------------------------------------------------
__global__ __launch_bounds__(256) void conv_w(
    const float* __restrict__ W, __hip_bfloat16* __restrict__ Wb)
{
    int i = blockIdx.x * 256 + threadIdx.x;
    float4 v = ((const float4*)W)[i];
    ushort4 o;
    o.x = bfbits(v.x); o.y = bfbits(v.y); o.z = bfbits(v.z); o.w = bfbits(v.w);
    ((ushort4*)Wb)[i] = o;
}

// ---------------------------------------------------------------------------
// Kernel 3: transpose g (B,H,L) bf16 -> gT (B,L,H) bf16
// ---------------------------------------------------------------------------
__global__ __launch_bounds__(256) void transpose_g(
    const __hip_bfloat16* __restrict__ g, __hip_bfloat16* __restrict__ gT)
{
    __shared__ __hip_bfloat16 t[64][66];
    const int tid = threadIdx.x;
    const int b  = blockIdx.z;
    const int h0 = blockIdx.x * 64;
    const int l0 = blockIdx.y * 64;

    #pragma unroll
    for (int q = 0; q < 2; ++q) {
        int idx = tid + q * 256;
        int r = idx >> 3, c8 = (idx & 7) * 8;
        uint4 v = *(const uint4*)(g + ((size_t)(b * HH + h0 + r)) * LL + l0 + c8);
        unsigned int* dst = (unsigned int*)&t[r][c8];
        dst[0] = v.x; dst[1] = v.y; dst[2] = v.z; dst[3] = v.w;
    }
    __syncthreads();
    #pragma unroll
    for (int q = 0; q < 2; ++q) {
        int idx = tid + q * 256;
        int r = idx >> 3, c8 = (idx & 7) * 8;
        unsigned short tmp[8];
        #pragma unroll
        for (int j = 0; j < 8; ++j) tmp[j] = *(unsigned short*)&t[c8 + j][r];
        uint4 o;
        o.x = (unsigned)tmp[0] | ((unsigned)tmp[1] << 16);
        o.y = (unsigned)tmp[2] | ((unsigned)tmp[3] << 16);
        o.z = (unsigned)tmp[4] | ((unsigned)tmp[5] << 16);
        o.w = (unsigned)tmp[6] | ((unsigned)tmp[7] << 16);
        *(uint4*)(gT + ((size_t)(b * LL + l0 + r)) * HH + h0 + c8) = o;
    }
}

// ---------------------------------------------------------------------------
// Kernel 4: out[b,o,l] = sum_i Wb[o,i] * gT[b,l,i] + bias[o]
// ---------------------------------------------------------------------------
__global__ __launch_bounds__(256) void out_gemm_mfma(
    const __hip_bfloat16* __restrict__ Wb,
    const __hip_bfloat16* __restrict__ gT,
    const float* __restrict__ bias,
    float* __restrict__ out)
{
    __shared__ __hip_bfloat16 As[128 * 64];
    __shared__ __hip_bfloat16 Bs[128 * 64];

    const int tid  = threadIdx.x;
    const int lane = tid & 63;
    const int wave = tid >> 6;
    const int wr = wave >> 1, wc = wave & 1;
    const int b  = blockIdx.z;
    const int o0 = blockIdx.x * 128;
    const int l0 = blockIdx.y * 128;

    const int srow = tid >> 3;
    const int scol = (tid & 7) * 8;

    f32x4 acc[4][4] = {};

    for (int kt = 0; kt < 16; ++kt) {
        const int k0 = kt * 64;
        __syncthreads();
        #pragma unroll
        for (int c = 0; c < 4; ++c) {
            int row = c * 32 + srow;
            const __hip_bfloat16* ga = Wb + (size_t)(o0 + row) * HH + k0 + scol;
            const __hip_bfloat16* gb = gT + ((size_t)(b * LL + l0 + row)) * HH + k0 + scol;
            __builtin_amdgcn_global_load_lds(
                (const __attribute__((address_space(1))) void*)ga,
                (__attribute__((address_space(3))) void*)(As + c * 2048 + wave * 512),
                16, 0, 0);
            __builtin_amdgcn_global_load_lds(
                (const __attribute__((address_space(1))) void*)gb,
                (__attribute__((address_space(3))) void*)(Bs + c * 2048 + wave * 512),
                16, 0, 0);
        }
        asm volatile("s_waitcnt vmcnt(0)" ::: "memory");
        __syncthreads();

        const int rA = wr * 64 + (lane & 15);
        const int rB = wc * 64 + (lane & 15);
        const int kf = (lane >> 4) * 8;
        bf16x8 af[4][2], bfr[4][2];
        #pragma unroll
        for (int m = 0; m < 4; ++m)
            #pragma unroll
            for (int ks = 0; ks < 2; ++ks)
                af[m][ks] = *(const bf16x8*)(As + (rA + m * 16) * 64 + ks * 32 + kf);
        #pragma unroll
        for (int n = 0; n < 4; ++n)
            #pragma unroll
            for (int ks = 0; ks < 2; ++ks)
                bfr[n][ks] = *(const bf16x8*)(Bs + (rB + n * 16) * 64 + ks * 32 + kf);
        #pragma unroll
        for (int m = 0; m < 4; ++m)
            #pragma unroll
            for (int n = 0; n < 4; ++n)
                #pragma unroll
                for (int ks = 0; ks < 2; ++ks)
                    acc[m][n] = __builtin_amdgcn_mfma_f32_16x16x32_bf16(
                        af[m][ks], bfr[n][ks], acc[m][n], 0, 0, 0);
    }

    #pragma unroll
    for (int m = 0; m < 4; ++m) {
        int obase = o0 + wr * 64 + m * 16 + (lane >> 4) * 4;
        #pragma unroll
        for (int n = 0; n < 4; ++n) {
            int l_ = l0 + wc * 64 + n * 16 + (lane & 15);
            #pragma unroll
            for (int r = 0; r < 4; ++r) {
                int o = obase + r;
                out[((size_t)(b * HH + o)) * LL + l_] = acc[m][n][r] + bias[o];
            }
        }
    }
}

extern "C" void kernel_launch(void* const* d_in, const int* in_sizes, int n_in,
                              void* d_out, int out_size, void* d_ws, size_t ws_size,
                              hipStream_t stream) {
    const float* u          = (const float*)d_in[0];
    const float* log_dt     = (const float*)d_in[1];
    const float* log_w_real = (const float*)d_in[2];
    const float* w_imag     = (const float*)d_in[3];
    const float* C_re       = (const float*)d_in[4];
    const float* C_im       = (const float*)d_in[5];
    const float* Dp         = (const float*)d_in[6];
    const float* W          = (const float*)d_in[7];
    const float* bias       = (const float*)d_in[8];
    float* out = (float*)d_out;

    __hip_bfloat16* g  = (__hip_bfloat16*)d_out;                        // stash in d_out slack
    __hip_bfloat16* gT = (__hip_bfloat16*)d_ws;                         // 33.5 MB
    __hip_bfloat16* Wb = (__hip_bfloat16*)((char*)d_ws + 33554432);     // 2 MB

    hipFuncSetAttribute((const void*)ssm_mfma,
                        hipFuncAttributeMaxDynamicSharedMemorySize, LDS_TOT);

    conv_w<<<dim3(HH * HH / 1024), 256, 0, stream>>>(W, Wb);
    ssm_mfma<<<dim3(HH), 512, LDS_TOT, stream>>>(u, log_dt, log_w_real, w_imag,
                                                 C_re, C_im, Dp, g);
    transpose_g<<<dim3(HH / 64, LL / 64, BB), 256, 0, stream>>>(g, gT);
    out_gemm_mfma<<<dim3(HH / 128, LL / 128, BB), 256, 0, stream>>>(Wb, gT, bias, out);
}

// Round 6
// 106.920 us; speedup vs baseline: 9.1662x; 1.1786x over previous
//
#include <hip/hip_runtime.h>
#include <hip/hip_bf16.h>

#define HH 1024
#define LL 2048
#define BB 8
#define NN2 32     // complex modes
#define CT 128     // chunk size
#define NCH 16     // LL / CT

typedef short bf16x8 __attribute__((ext_vector_type(8)));
typedef float f32x4  __attribute__((ext_vector_type(4)));

static __device__ __forceinline__ unsigned short bfbits(float x) {
    __hip_bfloat16 h = __float2bfloat16(x);
    return *(unsigned short*)&h;
}
static __device__ __forceinline__ float f_from_bits(unsigned short b) {
    __hip_bfloat16 h; *(unsigned short*)&h = b; return __bfloat162float(h);
}
static __device__ __forceinline__ float2 cmul(float2 a, float2 b) {
    return make_float2(fmaf(-a.y, b.y, a.x * b.x), fmaf(a.y, b.x, a.x * b.y));
}

// ---------------- ssm LDS pool offsets (bytes) ----------------
#define OFF_U    0        // ushort U[128][128]   (32768)
#define OFF_UN   32768    // union 16KB: AJ -> K1/K2 -> AP
#define OFF_P    49152    // ushort P/CS[128][64] (16384)
#define OFF_KT   65536
#define OFF_DTA  66048
#define OFF_CN   66304
#define OFF_LO   66560    // float2 lo[32][8]
#define OFF_HI   68608    // float2 hi[32][17]
#define LDS_TOT  72960

#define SWZ(off, row) ((off) ^ (((row) & 7) << 4))

// ---------------------------------------------------------------------------
// Kernel 1: one block per h. All 8 batches. MFMA chunked-scan SSM + GELU.
// (unchanged from R5)
// ---------------------------------------------------------------------------
__global__ __launch_bounds__(512, 4) void ssm_mfma(
    const float* __restrict__ u, const float* __restrict__ log_dt,
    const float* __restrict__ log_w_real, const float* __restrict__ w_imag,
    const float* __restrict__ C_re, const float* __restrict__ C_im,
    const float* __restrict__ Dp, __hip_bfloat16* __restrict__ g_out)
{
    extern __shared__ char smem[];
    float2* dtA = (float2*)(smem + OFF_DTA);
    float2* Cn  = (float2*)(smem + OFF_CN);
    float*  kt  = (float*)(smem + OFF_KT);
    float2* lo  = (float2*)(smem + OFF_LO);
    float2* hi  = (float2*)(smem + OFF_HI);

    const int tid  = threadIdx.x;
    const int lane = tid & 63;
    const int wave = tid >> 6;
    const int wr4  = wave >> 1;
    const int wc2  = wave & 1;
    const int h    = blockIdx.x;

    float4 ureg[8];
    #pragma unroll
    for (int q = 0; q < 8; ++q) {
        int b = q, c4 = tid;
        ureg[q] = *(const float4*)(u + ((size_t)(b * HH + h)) * LL + c4 * 4);
    }
    if (tid < NN2) {
        int n = tid;
        float dt = expf(log_dt[h]);
        float wr = -expf(log_w_real[n]);
        float wi = w_imag[n];
        float dar = wr * dt, dai = wi * dt;
        dtA[n] = make_float2(dar, dai);
        float er = expf(dar);
        float sn, cs; sincosf(dai, &sn, &cs);
        float exr = er * cs - 1.0f, exi = er * sn;
        float den = wr * wr + wi * wi;
        float fr = (exr * wr + exi * wi) / den;
        float fi = (exi * wr - exr * wi) / den;
        float cre = C_re[h * NN2 + n], cim = C_im[h * NN2 + n];
        Cn[n] = make_float2(cre * fr - cim * fi, cre * fi + cim * fr);
    }
    __syncthreads();

    #pragma unroll
    for (int q = 0; q < 8; ++q) {
        int row = q * 16 + (tid >> 5);
        int j   = (tid & 31) * 4;
        ushort4 o;
        o.x = bfbits(ureg[q].x); o.y = bfbits(ureg[q].y);
        o.z = bfbits(ureg[q].z); o.w = bfbits(ureg[q].w);
        *(ushort4*)(smem + SWZ(OFF_U + row * 256 + j * 2, row)) = o;
    }
    for (int idx = tid; idx < 800; idx += 512) {
        int n, j, p;
        if (idx < 256) { n = idx >> 3; j = idx & 7; p = j; }
        else { int k = idx - 256; n = (k * 241) >> 12; j = k - n * 17; p = j << 3; }
        float2 dA = dtA[n];
        float mag = expf(dA.x * (float)p);
        float sn, cs; sincosf(dA.y * (float)p, &sn, &cs);
        float2 v = make_float2(mag * cs, mag * sn);
        if (idx < 256) lo[n * 8 + j] = v; else hi[n * 17 + j] = v;
    }
    __syncthreads();

    #pragma unroll
    for (int q = 0; q < 2; ++q) {
        int vidx = q * 512 + tid;
        int n = vidx >> 5, j0 = (vidx & 31) * 4;
        float2 a0, a1, a2, a3;
        {
            int p = 127 - j0;       a0 = cmul(lo[n * 8 + (p & 7)], hi[n * 17 + (p >> 3)]);
            p = 126 - j0;           a1 = cmul(lo[n * 8 + (p & 7)], hi[n * 17 + (p >> 3)]);
            p = 125 - j0;           a2 = cmul(lo[n * 8 + (p & 7)], hi[n * 17 + (p >> 3)]);
            p = 124 - j0;           a3 = cmul(lo[n * 8 + (p & 7)], hi[n * 17 + (p >> 3)]);
        }
        ushort4 re, im;
        re.x = bfbits(a0.x); re.y = bfbits(a1.x); re.z = bfbits(a2.x); re.w = bfbits(a3.x);
        im.x = bfbits(a0.y); im.y = bfbits(a1.y); im.z = bfbits(a2.y); im.w = bfbits(a3.y);
        int r0 = 2 * n, r1 = 2 * n + 1;
        *(ushort4*)(smem + SWZ(OFF_UN + r0 * 256 + j0 * 2, r0)) = re;
        *(ushort4*)(smem + SWZ(OFF_UN + r1 * 256 + j0 * 2, r1)) = im;
    }
    {
        int t = tid >> 2, nb = (tid & 3) * 8;
        float s = 0.f;
        #pragma unroll
        for (int i = 0; i < 8; ++i) {
            int n = nb + i;
            float2 a = cmul(lo[n * 8 + (t & 7)], hi[n * 17 + (t >> 3)]);
            float2 C = Cn[n];
            s += C.x * a.x - C.y * a.y;
        }
        s += __shfl_xor(s, 1);
        s += __shfl_xor(s, 2);
        if ((tid & 3) == 0) kt[t] = 2.0f * s;
    }
    __syncthreads();

    f32x4 accP[2][2] = {};
    #pragma unroll
    for (int ks = 0; ks < 4; ++ks) {
        int kf = ks * 32 + (lane >> 4) * 8;
        bf16x8 a0, a1, b0, b1;
        {
            int r = wr4 * 32 + (lane & 15);
            a0 = *(bf16x8*)(smem + SWZ(OFF_U + r * 256 + kf * 2, r));
            int r2 = r + 16;
            a1 = *(bf16x8*)(smem + SWZ(OFF_U + r2 * 256 + kf * 2, r2));
        }
        {
            int r = wc2 * 32 + (lane & 15);
            b0 = *(bf16x8*)(smem + SWZ(OFF_UN + r * 256 + kf * 2, r));
            int r2 = r + 16;
            b1 = *(bf16x8*)(smem + SWZ(OFF_UN + r2 * 256 + kf * 2, r2));
        }
        accP[0][0] = __builtin_amdgcn_mfma_f32_16x16x32_bf16(a0, b0, accP[0][0], 0, 0, 0);
        accP[0][1] = __builtin_amdgcn_mfma_f32_16x16x32_bf16(a0, b1, accP[0][1], 0, 0, 0);
        accP[1][0] = __builtin_amdgcn_mfma_f32_16x16x32_bf16(a1, b0, accP[1][0], 0, 0, 0);
        accP[1][1] = __builtin_amdgcn_mfma_f32_16x16x32_bf16(a1, b1, accP[1][1], 0, 0, 0);
    }
    __syncthreads();
    #pragma unroll
    for (int mt = 0; mt < 2; ++mt)
        #pragma unroll
        for (int nt = 0; nt < 2; ++nt)
            #pragma unroll
            for (int r = 0; r < 4; ++r) {
                int row = wr4 * 32 + mt * 16 + (lane >> 4) * 4 + r;
                int col = wc2 * 32 + nt * 16 + (lane & 15);
                *(unsigned short*)(smem + SWZ(OFF_P + row * 128 + col * 2, row)) =
                    bfbits(accP[mt][nt][r]);
            }
    __syncthreads();

    #pragma unroll
    for (int q = 0; q < 16; ++q) {
        int idx = q * 512 + tid;
        int ttr = idx >> 6, j = idx & 63;
        float val = (ttr >= j) ? kt[ttr - j] : 0.0f;
        *(unsigned short*)(smem + SWZ(OFF_UN + ttr * 128 + j * 2, ttr)) = bfbits(val);
    }
    if (tid < 256) {
        int b = tid >> 5, n = tid & 31;
        float2 C = Cn[n];
        float2 A = hi[n * 17 + 16];
        float sr = 0.f, si = 0.f;
        for (int c = 0; c < NCH; ++c) {
            int row = b * 16 + c;
            int off = SWZ(OFF_P + row * 128 + n * 4, row);
            unsigned int pv = *(unsigned int*)(smem + off);
            float pr = f_from_bits((unsigned short)(pv & 0xffff));
            float pi = f_from_bits((unsigned short)(pv >> 16));
            float csr = C.x * sr - C.y * si;
            float csi = C.x * si + C.y * sr;
            *(unsigned int*)(smem + off) =
                (unsigned)bfbits(csr) | ((unsigned)bfbits(csi) << 16);
            float nsr = A.x * sr - A.y * si + pr;
            float nsi = A.x * si + A.y * sr + pi;
            sr = nsr; si = nsi;
        }
    }
    __syncthreads();

    f32x4 acc[2][4] = {};
    #pragma unroll
    for (int ks = 0; ks < 2; ++ks) {
        int kf = ks * 32 + (lane >> 4) * 8;
        bf16x8 a0, a1, bv[4];
        {
            int r = wr4 * 32 + (lane & 15);
            a0 = *(bf16x8*)(smem + SWZ(OFF_U + r * 256 + kf * 2, r));
            int r2 = r + 16;
            a1 = *(bf16x8*)(smem + SWZ(OFF_U + r2 * 256 + kf * 2, r2));
        }
        #pragma unroll
        for (int nt = 0; nt < 4; ++nt) {
            int ttr = wc2 * 64 + nt * 16 + (lane & 15);
            bv[nt] = *(bf16x8*)(smem + SWZ(OFF_UN + ttr * 128 + kf * 2, ttr));
        }
        #pragma unroll
        for (int nt = 0; nt < 4; ++nt) {
            acc[0][nt] = __builtin_amdgcn_mfma_f32_16x16x32_bf16(a0, bv[nt], acc[0][nt], 0, 0, 0);
            acc[1][nt] = __builtin_amdgcn_mfma_f32_16x16x32_bf16(a1, bv[nt], acc[1][nt], 0, 0, 0);
        }
    }
    __syncthreads();

    #pragma unroll
    for (int q = 0; q < 16; ++q) {
        int idx = q * 512 + tid;
        int ttr = idx >> 6, j = idx & 63;
        float val = (ttr >= 64 + j) ? kt[ttr - 64 - j] : 0.0f;
        *(unsigned short*)(smem + SWZ(OFF_UN + ttr * 128 + j * 2, ttr)) = bfbits(val);
    }
    __syncthreads();
    #pragma unroll
    for (int ks = 0; ks < 2; ++ks) {
        int kf = ks * 32 + (lane >> 4) * 8;
        bf16x8 a0, a1, bv[4];
        {
            int r = wr4 * 32 + (lane & 15);
            a0 = *(bf16x8*)(smem + SWZ(OFF_U + r * 256 + 128 + kf * 2, r));
            int r2 = r + 16;
            a1 = *(bf16x8*)(smem + SWZ(OFF_U + r2 * 256 + 128 + kf * 2, r2));
        }
        #pragma unroll
        for (int nt = 0; nt < 4; ++nt) {
            int ttr = wc2 * 64 + nt * 16 + (lane & 15);
            bv[nt] = *(bf16x8*)(smem + SWZ(OFF_UN + ttr * 128 + kf * 2, ttr));
        }
        #pragma unroll
        for (int nt = 0; nt < 4; ++nt) {
            acc[0][nt] = __builtin_amdgcn_mfma_f32_16x16x32_bf16(a0, bv[nt], acc[0][nt], 0, 0, 0);
            acc[1][nt] = __builtin_amdgcn_mfma_f32_16x16x32_bf16(a1, bv[nt], acc[1][nt], 0, 0, 0);
        }
    }
    __syncthreads();

    #pragma unroll
    for (int q = 0; q < 8; ++q) {
        int idx = q * 512 + tid;
        int n = idx >> 7, ttr = idx & 127;
        int p = ttr + 1;
        float2 a = cmul(lo[n * 8 + (p & 7)], hi[n * 17 + (p >> 3)]);
        int off = SWZ(OFF_UN + ttr * 128 + n * 4, ttr);
        *(unsigned int*)(smem + off) =
            (unsigned)bfbits(2.0f * a.x) | ((unsigned)bfbits(-2.0f * a.y) << 16);
    }
    __syncthreads();
    #pragma unroll
    for (int ks = 0; ks < 2; ++ks) {
        int kf = ks * 32 + (lane >> 4) * 8;
        bf16x8 a0, a1, bv[4];
        {
            int r = wr4 * 32 + (lane & 15);
            a0 = *(bf16x8*)(smem + SWZ(OFF_P + r * 128 + kf * 2, r));
            int r2 = r + 16;
            a1 = *(bf16x8*)(smem + SWZ(OFF_P + r2 * 128 + kf * 2, r2));
        }
        #pragma unroll
        for (int nt = 0; nt < 4; ++nt) {
            int ttr = wc2 * 64 + nt * 16 + (lane & 15);
            bv[nt] = *(bf16x8*)(smem + SWZ(OFF_UN + ttr * 128 + kf * 2, ttr));
        }
        #pragma unroll
        for (int nt = 0; nt < 4; ++nt) {
            acc[0][nt] = __builtin_amdgcn_mfma_f32_16x16x32_bf16(a0, bv[nt], acc[0][nt], 0, 0, 0);
            acc[1][nt] = __builtin_amdgcn_mfma_f32_16x16x32_bf16(a1, bv[nt], acc[1][nt], 0, 0, 0);
        }
    }

    const float Dv = Dp[h];
    #pragma unroll
    for (int mt = 0; mt < 2; ++mt)
        #pragma unroll
        for (int nt = 0; nt < 4; ++nt)
            #pragma unroll
            for (int r = 0; r < 4; ++r) {
                int row = wr4 * 32 + mt * 16 + (lane >> 4) * 4 + r;
                int ttr = wc2 * 64 + nt * 16 + (lane & 15);
                int off = SWZ(OFF_U + row * 256 + ttr * 2, row);
                float uv = f_from_bits(*(unsigned short*)(smem + off));
                float y = acc[mt][nt][r] + Dv * uv;
                float z = 0.7978845608f * (y + 0.044715f * y * y * y);
                float e = __expf(2.0f * z);
                float th = 1.0f - 2.0f / (e + 1.0f);
                float gel = 0.5f * y * (1.0f + th);
                *(unsigned short*)(smem + off) = bfbits(gel);
            }
    __syncthreads();
    #pragma unroll
    for (int q = 0; q < 4; ++q) {
        int flat = q * 512 + tid;
        int row = flat >> 4, c16 = flat & 15;
        uint4 v = *(uint4*)(smem + SWZ(OFF_U + row * 256 + c16 * 16, row));
        int b = row >> 4, c = row & 15;
        *(uint4*)(g_out + ((size_t)(b * HH + h)) * LL + c * CT + c16 * 8) = v;
    }
}

// ---------------------------------------------------------------------------
// Kernel 2: W (1024x1024 fp32) -> bf16
// ---------------------------------------------------------------------------
__global__ __launch_bounds__(256) void conv_w(
    const float* __restrict__ W, __hip_bfloat16* __restrict__ Wb)
{
    int i = blockIdx.x * 256 + threadIdx.x;
    float4 v = ((const float4*)W)[i];
    ushort4 o;
    o.x = bfbits(v.x); o.y = bfbits(v.y); o.z = bfbits(v.z); o.w = bfbits(v.w);
    ((ushort4*)Wb)[i] = o;
}

// ---------------------------------------------------------------------------
// Kernel 3: transpose g (B,H,L) bf16 -> gT (B,L,H) bf16
// ---------------------------------------------------------------------------
__global__ __launch_bounds__(256) void transpose_g(
    const __hip_bfloat16* __restrict__ g, __hip_bfloat16* __restrict__ gT)
{
    __shared__ __hip_bfloat16 t[64][66];
    const int tid = threadIdx.x;
    const int b  = blockIdx.z;
    const int h0 = blockIdx.x * 64;
    const int l0 = blockIdx.y * 64;

    #pragma unroll
    for (int q = 0; q < 2; ++q) {
        int idx = tid + q * 256;
        int r = idx >> 3, c8 = (idx & 7) * 8;
        uint4 v = *(const uint4*)(g + ((size_t)(b * HH + h0 + r)) * LL + l0 + c8);
        unsigned int* dst = (unsigned int*)&t[r][c8];
        dst[0] = v.x; dst[1] = v.y; dst[2] = v.z; dst[3] = v.w;
    }
    __syncthreads();
    #pragma unroll
    for (int q = 0; q < 2; ++q) {
        int idx = tid + q * 256;
        int r = idx >> 3, c8 = (idx & 7) * 8;
        unsigned short tmp[8];
        #pragma unroll
        for (int j = 0; j < 8; ++j) tmp[j] = *(unsigned short*)&t[c8 + j][r];
        uint4 o;
        o.x = (unsigned)tmp[0] | ((unsigned)tmp[1] << 16);
        o.y = (unsigned)tmp[2] | ((unsigned)tmp[3] << 16);
        o.z = (unsigned)tmp[4] | ((unsigned)tmp[5] << 16);
        o.w = (unsigned)tmp[6] | ((unsigned)tmp[7] << 16);
        *(uint4*)(gT + ((size_t)(b * LL + l0 + r)) * HH + h0 + c8) = o;
    }
}

// ---------------------------------------------------------------------------
// Kernel 4: out = Wb x gT^T + bias.  256x256 tile, BK=64, 8 waves, dbuf LDS,
// counted vmcnt (never 0 in loop), XOR-swizzled LDS, XCD-swizzled grid.
// A = Wb[1024][1024], B = gT[16384][1024], C = out (B,H,L) fp32.
// ---------------------------------------------------------------------------
#define GSLOT 32768                 // bytes per operand slot (256x64 bf16)
// stage tile (k-index kt) into slot s: 8 global_load_lds per thread
#define STAGE_TILE(kt_, s_)                                                      \
    {                                                                            \
        const int k0_ = (kt_) * 64;                                              \
        _Pragma("unroll")                                                        \
        for (int v_ = 0; v_ < 4; ++v_) {                                         \
            int row_ = v_ * 64 + rsub;                                           \
            const __hip_bfloat16* ga_ = Wb + (size_t)(o0 + row_) * HH + k0_ + csw; \
            const __hip_bfloat16* gb_ = gT + (size_t)(n0 + row_) * HH + k0_ + csw; \
            char* dA_ = smem + (s_) * GSLOT + (v_ * 64 + wave * 8) * 128;        \
            char* dB_ = smem + 2 * GSLOT + (s_) * GSLOT + (v_ * 64 + wave * 8) * 128; \
            __builtin_amdgcn_global_load_lds(                                    \
                (const __attribute__((address_space(1))) void*)ga_,              \
                (__attribute__((address_space(3))) void*)dA_, 16, 0, 0);         \
            __builtin_amdgcn_global_load_lds(                                    \
                (const __attribute__((address_space(1))) void*)gb_,              \
                (__attribute__((address_space(3))) void*)dB_, 16, 0, 0);         \
        }                                                                        \
    }

#define COMPUTE_TILE(s_)                                                         \
    {                                                                            \
        const char* baseA = smem + (s_) * GSLOT;                                 \
        const char* baseB = smem + 2 * GSLOT + (s_) * GSLOT;                     \
        bf16x8 bfr[4][2];                                                        \
        _Pragma("unroll")                                                        \
        for (int nt = 0; nt < 4; ++nt)                                           \
            _Pragma("unroll")                                                    \
            for (int ks = 0; ks < 2; ++ks) {                                     \
                int rb = wn * 64 + nt * 16 + (lane & 15);                        \
                int c  = (ks * 32 + (lane >> 4) * 8) ^ ((rb & 7) << 3);          \
                bfr[nt][ks] = *(const bf16x8*)(baseB + rb * 128 + c * 2);        \
            }                                                                    \
        _Pragma("unroll")                                                        \
        for (int qq = 0; qq < 4; ++qq) {                                         \
            bf16x8 af[2][2];                                                     \
            _Pragma("unroll")                                                    \
            for (int mt = 0; mt < 2; ++mt)                                       \
                _Pragma("unroll")                                                \
                for (int ks = 0; ks < 2; ++ks) {                                 \
                    int ra = wm * 128 + (qq * 2 + mt) * 16 + (lane & 15);        \
                    int c  = (ks * 32 + (lane >> 4) * 8) ^ ((ra & 7) << 3);      \
                    af[mt][ks] = *(const bf16x8*)(baseA + ra * 128 + c * 2);     \
                }                                                                \
            __builtin_amdgcn_s_setprio(1);                                       \
            _Pragma("unroll")                                                    \
            for (int mt = 0; mt < 2; ++mt)                                       \
                _Pragma("unroll")                                                \
                for (int nt = 0; nt < 4; ++nt) {                                 \
                    acc[qq * 2 + mt][nt] = __builtin_amdgcn_mfma_f32_16x16x32_bf16( \
                        af[mt][0], bfr[nt][0], acc[qq * 2 + mt][nt], 0, 0, 0);   \
                    acc[qq * 2 + mt][nt] = __builtin_amdgcn_mfma_f32_16x16x32_bf16( \
                        af[mt][1], bfr[nt][1], acc[qq * 2 + mt][nt], 0, 0, 0);   \
                }                                                                \
            __builtin_amdgcn_s_setprio(0);                                       \
        }                                                                        \
    }

__global__ __launch_bounds__(512, 2) void out_gemm_256(
    const __hip_bfloat16* __restrict__ Wb,
    const __hip_bfloat16* __restrict__ gT,
    const float* __restrict__ bias,
    float* __restrict__ out)
{
    extern __shared__ char smem[];
    const int tid  = threadIdx.x;
    const int lane = tid & 63;
    const int wave = tid >> 6;
    const int wm = wave >> 2;           // 0..1 : 128 M-rows
    const int wn = wave & 3;            // 0..3 : 64 N-rows

    // XCD-aware swizzle: 256 wgs, 8 XCDs, 32 per XCD
    int wg  = blockIdx.x;
    int swz = (wg & 7) * 32 + (wg >> 3);
    const int o0 = (swz & 3) * 256;     // M tile (4)
    const int n0 = (swz >> 2) * 256;    // N tile (64) over flattened (b,l)

    const int rsub = tid >> 3;                          // 0..63
    const int csw  = ((tid & 7) ^ (rsub & 7)) << 3;     // swizzled k col (elems)

    f32x4 acc[8][4] = {};

    // prologue: stage tiles 0,1
    STAGE_TILE(0, 0)
    STAGE_TILE(1, 1)

    for (int t = 0; t < 15; ++t) {
        asm volatile("s_waitcnt vmcnt(8)" ::: "memory");   // tile t landed; t+1 in flight
        __builtin_amdgcn_s_barrier();
        __builtin_amdgcn_sched_barrier(0);
        COMPUTE_TILE(t & 1)
        asm volatile("s_waitcnt lgkmcnt(0)" ::: "memory");
        __builtin_amdgcn_s_barrier();
        __builtin_amdgcn_sched_barrier(0);
        if (t < 14) STAGE_TILE(t + 2, t & 1)
    }
    asm volatile("s_waitcnt vmcnt(0)" ::: "memory");
    __builtin_amdgcn_s_barrier();
    __builtin_amdgcn_sched_barrier(0);
    COMPUTE_TILE(1)

    // epilogue: bias + store. n = (b,l) flattened; b const per block.
    const int bb = n0 >> 11;
    #pragma unroll
    for (int m = 0; m < 8; ++m) {
        int o = o0 + wm * 128 + m * 16 + (lane >> 4) * 4;
        #pragma unroll
        for (int nt = 0; nt < 4; ++nt) {
            int n = n0 + wn * 64 + nt * 16 + (lane & 15);
            int l = n & 2047;
            #pragma unroll
            for (int r = 0; r < 4; ++r)
                out[((size_t)(bb * HH + o + r)) * LL + l] = acc[m][nt][r] + bias[o + r];
        }
    }
}

extern "C" void kernel_launch(void* const* d_in, const int* in_sizes, int n_in,
                              void* d_out, int out_size, void* d_ws, size_t ws_size,
                              hipStream_t stream) {
    const float* u          = (const float*)d_in[0];
    const float* log_dt     = (const float*)d_in[1];
    const float* log_w_real = (const float*)d_in[2];
    const float* w_imag     = (const float*)d_in[3];
    const float* C_re       = (const float*)d_in[4];
    const float* C_im       = (const float*)d_in[5];
    const float* Dp         = (const float*)d_in[6];
    const float* W          = (const float*)d_in[7];
    const float* bias       = (const float*)d_in[8];
    float* out = (float*)d_out;

    __hip_bfloat16* g  = (__hip_bfloat16*)d_out;                        // stash in d_out slack
    __hip_bfloat16* gT = (__hip_bfloat16*)d_ws;                         // 33.5 MB
    __hip_bfloat16* Wb = (__hip_bfloat16*)((char*)d_ws + 33554432);     // 2 MB

    hipFuncSetAttribute((const void*)ssm_mfma,
                        hipFuncAttributeMaxDynamicSharedMemorySize, LDS_TOT);
    hipFuncSetAttribute((const void*)out_gemm_256,
                        hipFuncAttributeMaxDynamicSharedMemorySize, 131072);

    conv_w<<<dim3(HH * HH / 1024), 256, 0, stream>>>(W, Wb);
    ssm_mfma<<<dim3(HH), 512, LDS_TOT, stream>>>(u, log_dt, log_w_real, w_imag,
                                                 C_re, C_im, Dp, g);
    transpose_g<<<dim3(HH / 64, LL / 64, BB), 256, 0, stream>>>(g, gT);
    out_gemm_256<<<dim3(256), 512, 131072, stream>>>(Wb, gT, bias, out);
}